// Round 4
// baseline (1067.493 us; speedup 1.0000x reference)
//
#include <hip/hip_runtime.h>
#include <hip/hip_bf16.h>
#include <math.h>

// ---------------- problem constants ----------------
#define D_MODEL 1024
#define N_EXP   8
#define D_FF    4096
#define T_TOK   8192
#define NPAIR   (T_TOK * 2)              // 16384 token-expert pairs (top-2)
#define CAP_ROWS (NPAIR + N_EXP * 128)   // 17408: worst-case padded rows
#define MAX_TILES (CAP_ROWS / 128)       // 136 M-tiles (divisible by 8)
#define SLOT 49152                       // per ring slot: A 16K + B 32K

typedef __attribute__((ext_vector_type(4)))  float  f32x4;
typedef __attribute__((ext_vector_type(16))) float  f32x16;
typedef __attribute__((ext_vector_type(8)))  __bf16 bf16x8;
typedef __attribute__((ext_vector_type(4)))  __bf16 bf16x4;

// ---------------- workspace layout (bytes) ----------------
#define OFF_W1T   0
#define OFF_W2T   67108864
#define OFF_H     134217728
#define OFF_XR    276824064
#define OFF_META  312475648
#define M_PAIREXP 0         // int[16384]
#define M_PAIRW   65536     // float[16384]
#define M_ROW2P   131072    // int[17408]
#define M_COUNTS  200704    // int[8]
#define M_PADST   200736    // int[8]
#define M_CURSOR  200768    // int[8*32]
#define M_T2E     201792    // int[136]
#define M_TROW    202336    // int[136]

__device__ __forceinline__ void async_copy16(const void* g, void* s) {
  __builtin_amdgcn_global_load_lds(
      (const __attribute__((address_space(1))) void*)g,
      (__attribute__((address_space(3))) void*)s, 16, 0, 0);
}

__device__ __forceinline__ float gelu_fast(float v) {
  float u = 1.5957691216057308f * (v + 0.044715f * v * v * v);
  return v * __builtin_amdgcn_rcpf(1.f + __expf(-u));
}

// ---------------- gating ----------------
__global__ void k_gate(const float* __restrict__ x, const float* __restrict__ Wg,
                       const float* __restrict__ bg, float* __restrict__ logits_out,
                       int* __restrict__ pairExpert, float* __restrict__ pairW) {
  const int t    = blockIdx.x * 4 + (threadIdx.x >> 6);
  const int lane = threadIdx.x & 63;
  const float* xp = x + (size_t)t * D_MODEL;
  float acc[8];
#pragma unroll
  for (int e = 0; e < 8; e++) acc[e] = 0.f;
#pragma unroll
  for (int i = 0; i < 16; i++) {
    int d = i * 64 + lane;
    float xv = xp[d];
    const float4* wr = (const float4*)(Wg + d * 8);
    float4 w0 = wr[0], w1 = wr[1];
    acc[0] += xv * w0.x; acc[1] += xv * w0.y; acc[2] += xv * w0.z; acc[3] += xv * w0.w;
    acc[4] += xv * w1.x; acc[5] += xv * w1.y; acc[6] += xv * w1.z; acc[7] += xv * w1.w;
  }
#pragma unroll
  for (int e = 0; e < 8; e++)
#pragma unroll
    for (int off = 32; off > 0; off >>= 1) acc[e] += __shfl_down(acc[e], off);
  if (lane == 0) {
    float l[8];
#pragma unroll
    for (int e = 0; e < 8; e++) { l[e] = acc[e] + bg[e]; logits_out[t * 8 + e] = l[e]; }
    float m = l[0];
#pragma unroll
    for (int e = 1; e < 8; e++) m = fmaxf(m, l[e]);
    float p[8], s = 0.f;
#pragma unroll
    for (int e = 0; e < 8; e++) { p[e] = expf(l[e] - m); s += p[e]; }
    float inv = 1.0f / s;
    int i1 = 0;
#pragma unroll
    for (int e = 1; e < 8; e++) if (l[e] > l[i1]) i1 = e;
    int i2 = (i1 == 0) ? 1 : 0;
#pragma unroll
    for (int e = 0; e < 8; e++) if (e != i1 && l[e] > l[i2]) i2 = e;
    pairExpert[t * 2 + 0] = i1; pairW[t * 2 + 0] = p[i1] * inv;
    pairExpert[t * 2 + 1] = i2; pairW[t * 2 + 1] = p[i2] * inv;
  }
}

// ---------------- routing metadata ----------------
__global__ void k_init(int* __restrict__ row2pair) {
  int i = blockIdx.x * 256 + threadIdx.x;
  if (i < CAP_ROWS) row2pair[i] = -1;
}

__global__ void k_offsets(const int* __restrict__ pairExpert, int* __restrict__ counts,
                          int* __restrict__ padStart, int* __restrict__ cursor,
                          int* __restrict__ t2e, int* __restrict__ trow) {
  __shared__ int hist[8];
  int tid = threadIdx.x;
  if (tid < 8) hist[tid] = 0;
  __syncthreads();
  for (int i = tid; i < NPAIR; i += 256) atomicAdd(&hist[pairExpert[i]], 1);
  __syncthreads();
  if (tid == 0) {
    int run = 0, nt = 0;
    for (int e = 0; e < 8; e++) {
      counts[e] = hist[e]; padStart[e] = run; cursor[e * 32] = 0;
      int tiles = (hist[e] + 127) >> 7;
      for (int i = 0; i < tiles; i++) { t2e[nt] = e; trow[nt] = run + i * 128; nt++; }
      run += tiles * 128;
    }
    for (; nt < MAX_TILES; nt++) t2e[nt] = -1;
  }
}

__global__ void k_place(const int* __restrict__ pairExpert, const int* __restrict__ padStart,
                        int* __restrict__ cursor, int* __restrict__ row2pair) {
  int p = blockIdx.x * 256 + threadIdx.x;
  if (p >= NPAIR) return;
  int e = pairExpert[p];
  int r = atomicAdd(&cursor[e * 32], 1);
  row2pair[padStart[e] + r] = p;
}

// ---------------- gather x rows -> routed bf16 ----------------
__global__ void k_gather(const float* __restrict__ x, const int* __restrict__ row2pair,
                         __bf16* __restrict__ XR) {
  int row = blockIdx.x;
  int pair = row2pair[row];
  int c = threadIdx.x * 4;
  __bf16* dst = XR + (size_t)row * D_MODEL + c;
  if (pair < 0) {
    bf16x4 z = {(__bf16)0.f, (__bf16)0.f, (__bf16)0.f, (__bf16)0.f};
    *(bf16x4*)dst = z;
  } else {
    int t = pair >> 1;
    float4 v = *(const float4*)(x + (size_t)t * D_MODEL + c);
    bf16x4 o = {(__bf16)v.x, (__bf16)v.y, (__bf16)v.z, (__bf16)v.w};
    *(bf16x4*)dst = o;
  }
}

// ---------------- transpose-convert weights ----------------
__global__ void k_convT(const float* __restrict__ in, __bf16* __restrict__ out,
                        int R, int C) {
  __shared__ __bf16 tile[64][68];
  int e = blockIdx.z;
  const float* ip = in + (size_t)e * R * C + (size_t)(blockIdx.y * 64) * C + blockIdx.x * 64;
  __bf16* op = out + (size_t)e * R * C + (size_t)(blockIdx.x * 64) * R + blockIdx.y * 64;
#pragma unroll
  for (int it = 0; it < 4; it++) {
    int idx = it * 1024 + threadIdx.x * 4;
    int lr = idx >> 6, lc = idx & 63;
    float4 v = *(const float4*)(ip + (size_t)lr * C + lc);
    bf16x4 o = {(__bf16)v.x, (__bf16)v.y, (__bf16)v.z, (__bf16)v.w};
    *(bf16x4*)&tile[lr][lc] = o;
  }
  __syncthreads();
#pragma unroll
  for (int it = 0; it < 4; it++) {
    int idx = it * 1024 + threadIdx.x * 4;
    int lc = idx >> 6, lr = idx & 63;
    bf16x4 o = {tile[lr + 0][lc], tile[lr + 1][lc], tile[lr + 2][lc], tile[lr + 3][lc]};
    *(bf16x4*)(op + (size_t)lc * R + lr) = o;
  }
}

// =====================================================================
// m201-discipline phase machine. BM=128, BN=256, BK=64. 512 thr = 8 waves
// as 2M x 4N (wave tile 64x64, acc[2][2] f32x16). LDS: 3 slots x 48KB
// (A [4kq][128][32B] = 16K | B [4kq][256][32B] = 32K) = 144KB, 1 block/CU.
//
// Phase p of K-tile t:  { stage kq_p(t+2) (w<4: A+B, w>=4: B only);
//   ds_read frags for NEXT phase (reg ping-pong F0/F1); lgkmcnt(4);
//   sched_barrier(0); setprio(1); 4 MFMA (kc=p); setprio(0);
//   vmcnt(12|6); s_barrier }.
// Window algebra: stage of kq consumed at global-phase g+1 was issued at
// g-6; allowed outstanding after wait at g = 6 kq-stages = 12 loads (A+B
// wave) / 6 (B-only wave). Uniform every phase; never drains. Lead = 6
// phases (> HBM latency). Tail tiles re-stage tile NT-1 into the dead
// slot to keep counts uniform.
//
// LDS swizzle (both-sides, conflict-free): 16B granule g of row r stored
// at g ^ ((r>>2)&1) (flips the half-bit). Write side: gl_lds is linear, so
// lane l fetches global half hg = (l&1)^((l>>3)&1) of row (l>>1). Read:
// addr = kq*rows*32 + row*32 + ((half ^ ((row>>2)&1))<<4) -> granule%8
// distinct across any 8 consecutive rows => conflict-free b128.
// =====================================================================

template <int NT>
__device__ __forceinline__ void gemm_core(const char* gA, const char* gB,
                                          char* lds0, int w, bool wlow,
                                          int offA0, int offB0,
                                          f32x16 (&acc)[2][2]) {
#define STG_KQ(P, KB, SW)                                                  \
  do {                                                                     \
    if (wlow) async_copy16(gA + (KB) + (P) * 32,                           \
                           (SW) + (P) * 4096 + w * 1024);                  \
    async_copy16(gB + (KB) + (P) * 32,                                     \
                 (SW) + 16384 + (P) * 8192 + w * 1024);                    \
  } while (0)
#define RDF(A0, A1, B0, B1, RB, KC)                                        \
  do {                                                                     \
    A0 = *(const bf16x8*)((RB) + (KC) * 4096 + offA0);                     \
    A1 = *(const bf16x8*)((RB) + (KC) * 4096 + offA0 + 1024);              \
    B0 = *(const bf16x8*)((RB) + 16384 + (KC) * 8192 + offB0);             \
    B1 = *(const bf16x8*)((RB) + 16384 + (KC) * 8192 + offB0 + 1024);      \
  } while (0)
#define MM4(A0, A1, B0, B1)                                                \
  do {                                                                     \
    __builtin_amdgcn_s_setprio(1);                                         \
    acc[0][0] = __builtin_amdgcn_mfma_f32_32x32x16_bf16(A0, B0, acc[0][0], 0, 0, 0); \
    acc[0][1] = __builtin_amdgcn_mfma_f32_32x32x16_bf16(A0, B1, acc[0][1], 0, 0, 0); \
    acc[1][0] = __builtin_amdgcn_mfma_f32_32x32x16_bf16(A1, B0, acc[1][0], 0, 0, 0); \
    acc[1][1] = __builtin_amdgcn_mfma_f32_32x32x16_bf16(A1, B1, acc[1][1], 0, 0, 0); \
    __builtin_amdgcn_s_setprio(0);                                         \
  } while (0)
#define WBAR                                                               \
  do {                                                                     \
    if (wlow) asm volatile("s_waitcnt vmcnt(12)" ::: "memory");            \
    else      asm volatile("s_waitcnt vmcnt(6)" ::: "memory");             \
    __builtin_amdgcn_s_barrier();                                          \
    asm volatile("" ::: "memory");                                         \
  } while (0)
#define LG4                                                                \
  do {                                                                     \
    asm volatile("s_waitcnt lgkmcnt(4)" ::: "memory");                     \
    __builtin_amdgcn_sched_barrier(0);                                     \
  } while (0)

  bf16x8 F0a0, F0a1, F0b0, F0b1, F1a0, F1a1, F1b0, F1b1;
  const char* p0 = lds0;
  const char* p1 = lds0 + SLOT;
  const char* p2 = lds0 + 2 * SLOT;

  // prologue: stage tiles 0,1 fully; wait window; read kc0 frags of tile 0
#pragma unroll
  for (int p = 0; p < 4; p++) STG_KQ(p, 0, lds0);
#pragma unroll
  for (int p = 0; p < 4; p++) STG_KQ(p, 128, lds0 + SLOT);
  WBAR;
  RDF(F0a0, F0a1, F0b0, F0b1, p0, 0);

#pragma unroll 1
  for (int t = 0; t < NT; t++) {
    char* wb = (char*)p2;
    const size_t kb = (size_t)((t + 2 < NT) ? t + 2 : NT - 1) * 128;
    STG_KQ(0, kb, wb); RDF(F1a0, F1a1, F1b0, F1b1, p0, 1); LG4;
    MM4(F0a0, F0a1, F0b0, F0b1); WBAR;
    STG_KQ(1, kb, wb); RDF(F0a0, F0a1, F0b0, F0b1, p0, 2); LG4;
    MM4(F1a0, F1a1, F1b0, F1b1); WBAR;
    STG_KQ(2, kb, wb); RDF(F1a0, F1a1, F1b0, F1b1, p0, 3); LG4;
    MM4(F0a0, F0a1, F0b0, F0b1); WBAR;
    STG_KQ(3, kb, wb); RDF(F0a0, F0a1, F0b0, F0b1, p1, 0); LG4;
    MM4(F1a0, F1a1, F1b0, F1b1); WBAR;
    const char* tp = p0; p0 = p1; p1 = p2; p2 = tp;
  }
#undef STG_KQ
#undef RDF
#undef MM4
#undef WBAR
#undef LG4
}

// ---------------- GEMM1: H = gelu(XR @ W1[e] + b1[e]) -> bf16 ----------------
// grid = 136*16, bijective XCD swizzle: the 16 nb-siblings of one mt (sharing
// the A/XR panel) land on one XCD, temporally adjacent. 136 % 8 == 0.
__global__ __launch_bounds__(512, 1) void k_gemm1(
    const __bf16* __restrict__ XR, const __bf16* __restrict__ W1T,
    const float* __restrict__ b1, __bf16* __restrict__ H,
    const int* __restrict__ t2e, const int* __restrict__ trow) {
  __shared__ __align__(16) char lds[3 * SLOT];
  const int bid = blockIdx.x;
  const int xcd = bid & 7, q = bid >> 3;
  const int nb = q & 15;
  const int mt = (q >> 4) * 8 + xcd;
  const int e = t2e[mt];
  if (e < 0) return;
  const int rowBase = trow[mt];
  const int n0 = nb * 256;

  const int tid = threadIdx.x;
  const int l = tid & 63, w = tid >> 6;
  const bool wlow = w < 4;
  const int wm = (w >> 2) * 64, wn = (w & 3) * 64;
  const int l31 = l & 31, h = l >> 5;
  const int hg = (l & 1) ^ ((l >> 3) & 1);
  const int rowA0 = wm + l31, rowB0 = wn + l31;
  const int offA0 = rowA0 * 32 + ((h ^ ((rowA0 >> 2) & 1)) << 4);
  const int offB0 = rowB0 * 32 + ((h ^ ((rowB0 >> 2) & 1)) << 4);

  const char* gA = (const char*)(XR + (size_t)(rowBase + 32 * w + (l >> 1)) * D_MODEL) + hg * 16;
  const char* gB = (const char*)(W1T + (size_t)e * D_FF * D_MODEL
                                 + (size_t)(n0 + 32 * w + (l >> 1)) * D_MODEL) + hg * 16;

  f32x16 acc[2][2];
#pragma unroll
  for (int i = 0; i < 2; i++)
#pragma unroll
    for (int j = 0; j < 2; j++) acc[i][j] = (f32x16)(0.f);

  gemm_core<16>(gA, gB, lds, w, wlow, offA0, offB0, acc);

  // epilogue: C/D layout col=lane&31, row=(r&3)+8*(r>>2)+4*half
  int colv[2]; float biasv[2];
#pragma unroll
  for (int nj = 0; nj < 2; nj++) {
    colv[nj] = n0 + wn + nj * 32 + l31;
    biasv[nj] = b1[e * D_FF + colv[nj]];
  }
#pragma unroll
  for (int mi = 0; mi < 2; mi++)
#pragma unroll
    for (int r = 0; r < 16; r++) {
      size_t row = (size_t)rowBase + wm + mi * 32 + (r & 3) + 8 * (r >> 2) + 4 * h;
#pragma unroll
      for (int nj = 0; nj < 2; nj++)
        H[row * D_FF + colv[nj]] = (__bf16)gelu_fast(acc[mi][nj][r] + biasv[nj]);
    }
}

// ---------------- GEMM2: out[t] += w * (H @ W2[e] + b2[e])  (fused combine) ----
// grid = 136*4; same bijective XCD swizzle (4 nb-siblings share the H panel).
__global__ __launch_bounds__(512, 1) void k_gemm2(
    const __bf16* __restrict__ H, const __bf16* __restrict__ W2T,
    const float* __restrict__ b2, float* __restrict__ out,
    const int* __restrict__ row2pair, const float* __restrict__ pairW,
    const int* __restrict__ t2e, const int* __restrict__ trow) {
  __shared__ __align__(16) char lds[3 * SLOT];
  const int bid = blockIdx.x;
  const int xcd = bid & 7, q = bid >> 3;
  const int nb = q & 3;
  const int mt = (q >> 2) * 8 + xcd;
  const int e = t2e[mt];
  if (e < 0) return;
  const int rowBase = trow[mt];
  const int n0 = nb * 256;

  const int tid = threadIdx.x;
  const int l = tid & 63, w = tid >> 6;
  const bool wlow = w < 4;
  const int wm = (w >> 2) * 64, wn = (w & 3) * 64;
  const int l31 = l & 31, h = l >> 5;
  const int hg = (l & 1) ^ ((l >> 3) & 1);
  const int rowA0 = wm + l31, rowB0 = wn + l31;
  const int offA0 = rowA0 * 32 + ((h ^ ((rowA0 >> 2) & 1)) << 4);
  const int offB0 = rowB0 * 32 + ((h ^ ((rowB0 >> 2) & 1)) << 4);

  const char* gA = (const char*)(H + (size_t)(rowBase + 32 * w + (l >> 1)) * D_FF) + hg * 16;
  const char* gB = (const char*)(W2T + (size_t)e * D_MODEL * D_FF
                                 + (size_t)(n0 + 32 * w + (l >> 1)) * D_FF) + hg * 16;

  f32x16 acc[2][2];
#pragma unroll
  for (int i = 0; i < 2; i++)
#pragma unroll
    for (int j = 0; j < 2; j++) acc[i][j] = (f32x16)(0.f);

  gemm_core<64>(gA, gB, lds, w, wlow, offA0, offB0, acc);

  // epilogue: fused combine — 2 commutative fp32 atomic adds per element
  int colv[2]; float biasv[2];
#pragma unroll
  for (int nj = 0; nj < 2; nj++) {
    colv[nj] = n0 + wn + nj * 32 + l31;
    biasv[nj] = b2[e * D_MODEL + colv[nj]];
  }
#pragma unroll
  for (int mi = 0; mi < 2; mi++)
#pragma unroll
    for (int r = 0; r < 16; r++) {
      int row = rowBase + wm + mi * 32 + (r & 3) + 8 * (r >> 2) + 4 * h;
      int pair = row2pair[row];
      if (pair < 0) continue;
      float pw = pairW[pair];
      size_t tok = (size_t)(pair >> 1);
#pragma unroll
      for (int nj = 0; nj < 2; nj++)
        atomicAdd(out + tok * D_MODEL + colv[nj], pw * (acc[mi][nj][r] + biasv[nj]));
    }
}

extern "C" void kernel_launch(void* const* d_in, const int* in_sizes, int n_in,
                              void* d_out, int out_size, void* d_ws, size_t ws_size,
                              hipStream_t stream) {
  const float* x  = (const float*)d_in[0];
  const float* Wg = (const float*)d_in[1];
  const float* bg = (const float*)d_in[2];
  const float* W1 = (const float*)d_in[3];
  const float* b1 = (const float*)d_in[4];
  const float* W2 = (const float*)d_in[5];
  const float* b2 = (const float*)d_in[6];
  float* out        = (float*)d_out;
  float* logits_out = out + (size_t)T_TOK * D_MODEL;

  char* ws = (char*)d_ws;
  __bf16* W1T = (__bf16*)(ws + OFF_W1T);
  __bf16* W2T = (__bf16*)(ws + OFF_W2T);
  __bf16* H   = (__bf16*)(ws + OFF_H);
  __bf16* XR  = (__bf16*)(ws + OFF_XR);
  char* meta = ws + OFF_META;
  int*   pairExpert = (int*)(meta + M_PAIREXP);
  float* pairW      = (float*)(meta + M_PAIRW);
  int*   row2pair   = (int*)(meta + M_ROW2P);
  int*   counts     = (int*)(meta + M_COUNTS);
  int*   padStart   = (int*)(meta + M_PADST);
  int*   cursor     = (int*)(meta + M_CURSOR);
  int*   t2e        = (int*)(meta + M_T2E);
  int*   trow       = (int*)(meta + M_TROW);

  // zero the combined output (gemm2 accumulates into it atomically)
  hipMemsetAsync(out, 0, (size_t)T_TOK * D_MODEL * sizeof(float), stream);

  k_convT<<<dim3(D_FF / 64, D_MODEL / 64, N_EXP), 256, 0, stream>>>(W1, W1T, D_MODEL, D_FF);
  k_convT<<<dim3(D_MODEL / 64, D_FF / 64, N_EXP), 256, 0, stream>>>(W2, W2T, D_FF, D_MODEL);

  k_init<<<(CAP_ROWS + 255) / 256, 256, 0, stream>>>(row2pair);
  k_gate<<<T_TOK / 4, 256, 0, stream>>>(x, Wg, bg, logits_out, pairExpert, pairW);
  k_offsets<<<1, 256, 0, stream>>>(pairExpert, counts, padStart, cursor, t2e, trow);
  k_place<<<NPAIR / 256, 256, 0, stream>>>(pairExpert, padStart, cursor, row2pair);
  k_gather<<<CAP_ROWS, 256, 0, stream>>>(x, row2pair, XR);

  k_gemm1<<<MAX_TILES * 16, 512, 0, stream>>>(XR, W1T, b1, H, t2e, trow);
  k_gemm2<<<MAX_TILES * 4, 512, 0, stream>>>(H, W2T, b2, out, row2pair, pairW, t2e, trow);
}